// Round 1
// baseline (845.542 us; speedup 1.0000x reference)
//
#include <hip/hip_runtime.h>
#include <hip/hip_bf16.h>

#define RREL 4
#define DIM 256
#define KDIM 1280   // 4*DIM + DIM (means per relation + self)

__device__ __forceinline__ float bf2f(unsigned short u) {
    union { unsigned int i; float f; } z; z.i = ((unsigned int)u) << 16; return z.f;
}

// ---------------- CSR build ----------------

__global__ void count_edges(const int* __restrict__ etype, const int* __restrict__ dst,
                            int* __restrict__ counts, int N, int E) {
    int e = blockIdx.x * 256 + threadIdx.x;
    if (e < E) atomicAdd(&counts[etype[e] * N + dst[e]], 1);
}

__device__ __forceinline__ int wave_scan_incl(int v) {
    int lane = threadIdx.x & 63;
#pragma unroll
    for (int off = 1; off < 64; off <<= 1) {
        int n = __shfl_up(v, off, 64);
        if (lane >= off) v += n;
    }
    return v;
}

// inclusive scan across a 256-thread block
__device__ __forceinline__ int block_scan_256(int v) {
    __shared__ int wsm[8];
    int lane = threadIdx.x & 63;
    int wid = threadIdx.x >> 6;
    int incl = wave_scan_incl(v);
    if (lane == 63) wsm[wid] = incl;
    __syncthreads();
    if (threadIdx.x == 0) {
        int s = 0;
#pragma unroll
        for (int w = 0; w < 4; w++) { int t = wsm[w]; wsm[4 + w] = s; s += t; }
    }
    __syncthreads();
    return incl + wsm[4 + wid];
}

__global__ void scan_part1(const int* __restrict__ counts, int n, int* __restrict__ bsums) {
    int i = blockIdx.x * 256 + threadIdx.x;
    int v = (i < n) ? counts[i] : 0;
    int incl = block_scan_256(v);
    if (threadIdx.x == 255) bsums[blockIdx.x] = incl;
}

__global__ void scan_part2(int* __restrict__ bsums, int nb) {  // 1 block, 512 threads; nb <= 512
    __shared__ int wsm[16];
    int t = threadIdx.x;
    int v = (t < nb) ? bsums[t] : 0;
    int lane = t & 63, wid = t >> 6;
    int incl = wave_scan_incl(v);
    if (lane == 63) wsm[wid] = incl;
    __syncthreads();
    if (t == 0) {
        int s = 0;
#pragma unroll
        for (int w = 0; w < 8; w++) { int tv = wsm[w]; wsm[8 + w] = s; s += tv; }
    }
    __syncthreads();
    incl += wsm[8 + wid];
    if (t < nb) bsums[t] = incl - v;   // exclusive
}

__global__ void scan_part3(const int* __restrict__ counts, int n,
                           const int* __restrict__ bsums, int* __restrict__ offsets) {
    int i = blockIdx.x * 256 + threadIdx.x;
    int v = (i < n) ? counts[i] : 0;
    int incl = block_scan_256(v);
    if (i < n) offsets[i] = bsums[blockIdx.x] + incl - v;
}

__global__ void scatter_edges(const int* __restrict__ etype, const int* __restrict__ src,
                              const int* __restrict__ dst, const int* __restrict__ offsets,
                              int* __restrict__ cursors, int* __restrict__ elist, int N, int E) {
    int e = blockIdx.x * 256 + threadIdx.x;
    if (e < E) {
        int seg = etype[e] * N + dst[e];
        int p = atomicAdd(&cursors[seg], 1);
        elist[offsets[seg] + p] = src[e];
    }
}

// ---------------- aggregation: Y[i] = [mean_r(feat) x4 | feat_i]  (bf16) ----------------

__global__ __launch_bounds__(256)
void aggregate(const float* __restrict__ feat, const int* __restrict__ offsets,
               const int* __restrict__ counts, const int* __restrict__ elist,
               __hip_bfloat16* __restrict__ Y, int N) {
    int i = blockIdx.x;
    int d = threadIdx.x;                 // 256 threads, one per feature dim
    float self = feat[(size_t)i * DIM + d];
#pragma unroll
    for (int r = 0; r < RREL; r++) {
        int seg = r * N + i;
        int beg = offsets[seg];
        int cnt = counts[seg];
        float s = 0.f;
        for (int k = 0; k < cnt; k++) {
            int sidx = elist[beg + k];
            s += feat[(size_t)sidx * DIM + d];
        }
        float m = (cnt > 0) ? s / (float)cnt : 0.f;
        Y[(size_t)i * KDIM + r * DIM + d] = __float2bfloat16(m);
    }
    Y[(size_t)i * KDIM + 4 * DIM + d] = __float2bfloat16(self);
}

// ---------------- GEMM: C[N,256] = Y[N,1280](bf16) @ [W;root](f32) + bias (opt ReLU) --------

#define BM 128
#define BN 64
#define BK 16

__global__ __launch_bounds__(256)
void gemm_bias(const __hip_bfloat16* __restrict__ Abf,
               const float* __restrict__ W,      // [1024,256]
               const float* __restrict__ Rt,     // [256,256]
               const float* __restrict__ bias,   // [256]
               float* __restrict__ C,            // [N,256]
               int N, int relu) {
    __shared__ float As[BK][BM];
    __shared__ float Bs[BK][BN];
    const unsigned short* A = (const unsigned short*)Abf;

    int t = threadIdx.x;
    int tx = t & 15, ty = t >> 4;
    int row0 = blockIdx.x * BM;
    int col0 = blockIdx.y * BN;

    float acc[8][4] = {};

    int a_tr = t >> 2;            // 0..63 (two rows: a_tr, a_tr+64)
    int a_tk = (t & 3) * 4;       // 0,4,8,12
    int b_n = t & 63;
    int b_kq = t >> 6;            // 0..3

    for (int k0 = 0; k0 < KDIM; k0 += BK) {
        // stage A (bf16 -> f32, transposed into As[k][m])
#pragma unroll
        for (int h = 0; h < 2; h++) {
            int r = a_tr + h * 64;
            int grow = row0 + r;
            ushort4 u = make_ushort4(0, 0, 0, 0);
            if (grow < N) u = *(const ushort4*)(A + (size_t)grow * KDIM + k0 + a_tk);
            As[a_tk + 0][r] = bf2f(u.x);
            As[a_tk + 1][r] = bf2f(u.y);
            As[a_tk + 2][r] = bf2f(u.z);
            As[a_tk + 3][r] = bf2f(u.w);
        }
        // stage B (choose W or root per k-tile; 1024 % BK == 0 so tiles never straddle)
        const float* Bp = (k0 < 1024) ? (W + (size_t)k0 * DIM + col0)
                                      : (Rt + (size_t)(k0 - 1024) * DIM + col0);
#pragma unroll
        for (int j = 0; j < 4; j++) {
            int kk = b_kq * 4 + j;
            Bs[kk][b_n] = Bp[(size_t)kk * DIM + b_n];
        }
        __syncthreads();

#pragma unroll
        for (int k = 0; k < BK; k++) {
            float a[8], b[4];
            *(float4*)&a[0] = *(const float4*)&As[k][ty * 8];
            *(float4*)&a[4] = *(const float4*)&As[k][ty * 8 + 4];
            *(float4*)&b[0] = *(const float4*)&Bs[k][tx * 4];
#pragma unroll
            for (int i = 0; i < 8; i++)
#pragma unroll
                for (int j = 0; j < 4; j++)
                    acc[i][j] += a[i] * b[j];
        }
        __syncthreads();
    }

    // epilogue
    float4 bv = *(const float4*)&bias[col0 + tx * 4];
    float bArr[4] = { bv.x, bv.y, bv.z, bv.w };
#pragma unroll
    for (int i = 0; i < 8; i++) {
        int grow = row0 + ty * 8 + i;
        if (grow < N) {
            float4 v;
            float* vp = (float*)&v;
#pragma unroll
            for (int j = 0; j < 4; j++) {
                float vv = acc[i][j] + bArr[j];
                if (relu) vv = fmaxf(vv, 0.f);
                vp[j] = vv;
            }
            *(float4*)&C[(size_t)grow * DIM + col0 + tx * 4] = v;
        }
    }
}

// ---------------- pooling + linear head ----------------

__global__ void colsum(const float* __restrict__ Hm, int N, float* __restrict__ g) {
    int t = threadIdx.x;       // 256 = one per column
    int r0 = blockIdx.x * 256;
    int rend = min(r0 + 256, N);
    float s = 0.f;
    for (int r = r0; r < rend; r++) s += Hm[(size_t)r * DIM + t];
    atomicAdd(&g[t], s);
}

__global__ void final_lin(const float* __restrict__ g, const float* __restrict__ lw,
                          const float* __restrict__ lb, float* __restrict__ out) {
    __shared__ float s0[256], s1[256];
    int t = threadIdx.x;
    float gv = g[t];
    s0[t] = gv * lw[t * 2 + 0];
    s1[t] = gv * lw[t * 2 + 1];
    __syncthreads();
    for (int off = 128; off > 0; off >>= 1) {
        if (t < off) { s0[t] += s0[t + off]; s1[t] += s1[t + off]; }
        __syncthreads();
    }
    if (t == 0) { out[0] = s0[0] + lb[0]; out[1] = s1[0] + lb[1]; }
}

// ---------------- launch ----------------

static inline char* align_up(char* p, size_t a) {
    return (char*)(((uintptr_t)p + (a - 1)) & ~(uintptr_t)(a - 1));
}

extern "C" void kernel_launch(void* const* d_in, const int* in_sizes, int n_in,
                              void* d_out, int out_size, void* d_ws, size_t ws_size,
                              hipStream_t stream) {
    const float* x     = (const float*)d_in[0];
    const int*   eidx  = (const int*)d_in[1];
    const int*   etype = (const int*)d_in[2];
    const float* W0    = (const float*)d_in[4];
    const float* root0 = (const float*)d_in[5];
    const float* b0    = (const float*)d_in[6];
    const float* W1    = (const float*)d_in[7];
    const float* root1 = (const float*)d_in[8];
    const float* b1    = (const float*)d_in[9];
    const float* lin_w = (const float*)d_in[10];
    const float* lin_b = (const float*)d_in[11];
    float* out = (float*)d_out;

    const int N = in_sizes[0] / DIM;
    const int E = in_sizes[2];
    const int RN = RREL * N;
    const int* src = eidx;
    const int* dst = eidx + E;

    char* w = (char*)d_ws;
    int* counts  = (int*)w; w += (size_t)RN * 4;
    int* cursors = (int*)w; w += (size_t)RN * 4;
    float* g     = (float*)w; w += 256 * 4;
    size_t zero_bytes = (size_t)RN * 8 + 1024;   // counts + cursors + g, contiguous
    int* offsets = (int*)w; w += (size_t)RN * 4;
    int nb = (RN + 255) / 256;
    int* bsums   = (int*)w; w += (size_t)nb * 4;
    int* elist   = (int*)w; w += (size_t)E * 4;
    w = align_up(w, 16);
    __hip_bfloat16* Y = (__hip_bfloat16*)w; w += (size_t)N * KDIM * 2;
    w = align_up(w, 16);
    float* h1 = (float*)w; w += (size_t)N * DIM * 4;
    float* h2 = (float*)w; w += (size_t)N * DIM * 4;

    hipMemsetAsync(counts, 0, zero_bytes, stream);

    int eb = (E + 255) / 256;
    count_edges<<<eb, 256, 0, stream>>>(etype, dst, counts, N, E);
    scan_part1<<<nb, 256, 0, stream>>>(counts, RN, bsums);
    scan_part2<<<1, 512, 0, stream>>>(bsums, nb);
    scan_part3<<<nb, 256, 0, stream>>>(counts, RN, bsums, offsets);
    scatter_edges<<<eb, 256, 0, stream>>>(etype, src, dst, offsets, cursors, elist, N, E);

    dim3 gg((N + BM - 1) / BM, DIM / BN);

    // layer 0
    aggregate<<<N, 256, 0, stream>>>(x, offsets, counts, elist, Y, N);
    gemm_bias<<<gg, 256, 0, stream>>>(Y, W0, root0, b0, h1, N, 1);
    // layer 1
    aggregate<<<N, 256, 0, stream>>>(h1, offsets, counts, elist, Y, N);
    gemm_bias<<<gg, 256, 0, stream>>>(Y, W1, root1, b1, h2, N, 0);

    // pool + head
    colsum<<<(N + 255) / 256, 256, 0, stream>>>(h2, N, g);
    final_lin<<<1, 256, 0, stream>>>(g, lin_w, lin_b, out);
}

// Round 2
// 372.556 us; speedup vs baseline: 2.2696x; 2.2696x over previous
//
#include <hip/hip_runtime.h>
#include <hip/hip_bf16.h>

#define RREL 4
#define DIM 256
#define KDIM 1280   // 4*DIM + DIM (means per relation + self)

__device__ __forceinline__ float bf2f(unsigned short u) {
    union { unsigned int i; float f; } z; z.i = ((unsigned int)u) << 16; return z.f;
}
__device__ __forceinline__ unsigned short f2bf(float f) {
    __hip_bfloat16 h = __float2bfloat16(f);
    return *(unsigned short*)&h;
}

// ---------------- CSR build ----------------

__global__ void count_edges(const int* __restrict__ etype, const int* __restrict__ dst,
                            int* __restrict__ counts, int N, int E) {
    int e = blockIdx.x * 256 + threadIdx.x;
    if (e < E) atomicAdd(&counts[etype[e] * N + dst[e]], 1);
}

__device__ __forceinline__ int wave_scan_incl(int v) {
    int lane = threadIdx.x & 63;
#pragma unroll
    for (int off = 1; off < 64; off <<= 1) {
        int n = __shfl_up(v, off, 64);
        if (lane >= off) v += n;
    }
    return v;
}

__device__ __forceinline__ int block_scan_256(int v) {
    __shared__ int wsm[8];
    int lane = threadIdx.x & 63;
    int wid = threadIdx.x >> 6;
    int incl = wave_scan_incl(v);
    if (lane == 63) wsm[wid] = incl;
    __syncthreads();
    if (threadIdx.x == 0) {
        int s = 0;
#pragma unroll
        for (int w = 0; w < 4; w++) { int t = wsm[w]; wsm[4 + w] = s; s += t; }
    }
    __syncthreads();
    return incl + wsm[4 + wid];
}

__global__ void scan_part1(const int* __restrict__ counts, int n, int* __restrict__ bsums) {
    int i = blockIdx.x * 256 + threadIdx.x;
    int v = (i < n) ? counts[i] : 0;
    int incl = block_scan_256(v);
    if (threadIdx.x == 255) bsums[blockIdx.x] = incl;
}

__global__ void scan_part2(int* __restrict__ bsums, int nb) {  // 1 block, 512 threads; nb <= 512
    __shared__ int wsm[16];
    int t = threadIdx.x;
    int v = (t < nb) ? bsums[t] : 0;
    int lane = t & 63, wid = t >> 6;
    int incl = wave_scan_incl(v);
    if (lane == 63) wsm[wid] = incl;
    __syncthreads();
    if (t == 0) {
        int s = 0;
#pragma unroll
        for (int w = 0; w < 8; w++) { int tv = wsm[w]; wsm[8 + w] = s; s += tv; }
    }
    __syncthreads();
    incl += wsm[8 + wid];
    if (t < nb) bsums[t] = incl - v;   // exclusive
}

__global__ void scan_part3(const int* __restrict__ counts, int n,
                           const int* __restrict__ bsums, int* __restrict__ offsets) {
    int i = blockIdx.x * 256 + threadIdx.x;
    int v = (i < n) ? counts[i] : 0;
    int incl = block_scan_256(v);
    if (i < n) offsets[i] = bsums[blockIdx.x] + incl - v;
}

__global__ void scatter_edges(const int* __restrict__ etype, const int* __restrict__ src,
                              const int* __restrict__ dst, const int* __restrict__ offsets,
                              int* __restrict__ cursors, int* __restrict__ elist, int N, int E) {
    int e = blockIdx.x * 256 + threadIdx.x;
    if (e < E) {
        int seg = etype[e] * N + dst[e];
        int p = atomicAdd(&cursors[seg], 1);
        elist[offsets[seg] + p] = src[e];
    }
}

// ---------------- weight transpose + bf16 cast: WT[layer][n][k] ----------------

__global__ __launch_bounds__(256)
void build_wt(const float* __restrict__ W0, const float* __restrict__ root0,
              const float* __restrict__ W1, const float* __restrict__ root1,
              __hip_bfloat16* __restrict__ WT) {
    __shared__ float tile[32][33];
    int layer = blockIdx.z;
    const float* Wm = layer ? W1 : W0;
    const float* Rm = layer ? root1 : root0;
    int k0 = blockIdx.x * 32, n0 = blockIdx.y * 32;
    int tx = threadIdx.x & 31, ty = threadIdx.x >> 5;   // 32x8
    const float* src;
    int kbase;
    if (k0 < RREL * DIM) { src = Wm; kbase = k0; } else { src = Rm; kbase = k0 - RREL * DIM; }
#pragma unroll
    for (int j = 0; j < 4; j++) {
        int k = kbase + ty + j * 8;
        tile[ty + j * 8][tx] = src[(size_t)k * DIM + n0 + tx];
    }
    __syncthreads();
#pragma unroll
    for (int j = 0; j < 4; j++) {
        int n = n0 + ty + j * 8;
        WT[((size_t)layer * DIM + n) * KDIM + k0 + tx] = __float2bfloat16(tile[tx][ty + j * 8]);
    }
}

// ---------------- aggregation: Y[i] = [mean_r(feat) x4 | feat_i]  (bf16) ----------------
// 320 threads = 5 waves: waves 0-3 handle relations, wave 4 copies the self row.
// Each lane owns 4 feature dims (float4); 4-deep unroll keeps 4 row-loads in flight.

__device__ __forceinline__ float4 load_row4(const float* f, size_t row, int lane) {
    return *(const float4*)(f + row * DIM + lane * 4);
}
__device__ __forceinline__ float4 load_row4(const __hip_bfloat16* f, size_t row, int lane) {
    const unsigned short* p = (const unsigned short*)f + row * DIM + lane * 4;
    ushort4 u = *(const ushort4*)p;
    float4 r;
    r.x = bf2f(u.x); r.y = bf2f(u.y); r.z = bf2f(u.z); r.w = bf2f(u.w);
    return r;
}

template <typename T>
__global__ __launch_bounds__(320)
void aggregate(const T* __restrict__ feat, const int* __restrict__ offsets,
               const int* __restrict__ counts, const int* __restrict__ elist,
               __hip_bfloat16* __restrict__ Y, int N) {
    int i = blockIdx.x;
    int wave = threadIdx.x >> 6, lane = threadIdx.x & 63;
    unsigned short* Yu = (unsigned short*)Y;
    if (wave == 4) {   // self row
        float4 v = load_row4(feat, (size_t)i, lane);
        ushort4 u = make_ushort4(f2bf(v.x), f2bf(v.y), f2bf(v.z), f2bf(v.w));
        *(ushort4*)(Yu + (size_t)i * KDIM + RREL * DIM + lane * 4) = u;
        return;
    }
    int seg = wave * N + i;
    int beg = offsets[seg];
    int cnt = counts[seg];
    float ax = 0.f, ay = 0.f, az = 0.f, aw = 0.f;
    int k = 0;
    for (; k + 4 <= cnt; k += 4) {
        int i0 = elist[beg + k + 0];
        int i1 = elist[beg + k + 1];
        int i2 = elist[beg + k + 2];
        int i3 = elist[beg + k + 3];
        float4 r0 = load_row4(feat, (size_t)i0, lane);
        float4 r1 = load_row4(feat, (size_t)i1, lane);
        float4 r2 = load_row4(feat, (size_t)i2, lane);
        float4 r3 = load_row4(feat, (size_t)i3, lane);
        ax += r0.x + r1.x + r2.x + r3.x;
        ay += r0.y + r1.y + r2.y + r3.y;
        az += r0.z + r1.z + r2.z + r3.z;
        aw += r0.w + r1.w + r2.w + r3.w;
    }
    for (; k < cnt; k++) {
        int idx = elist[beg + k];
        float4 r = load_row4(feat, (size_t)idx, lane);
        ax += r.x; ay += r.y; az += r.z; aw += r.w;
    }
    float inv = (cnt > 0) ? 1.f / (float)cnt : 0.f;
    ushort4 u = make_ushort4(f2bf(ax * inv), f2bf(ay * inv), f2bf(az * inv), f2bf(aw * inv));
    *(ushort4*)(Yu + (size_t)i * KDIM + wave * DIM + lane * 4) = u;
}

// ---------------- MFMA GEMM: C[N,256] = Y[Mpad,1280](bf16) @ WT^T + bias ----------------
// Tile 128x128, BK=32, 256 threads = 4 waves in 2x2; wave computes 64x64 via
// 4x4 fragments of mfma_f32_16x16x32_bf16. global_load_lds width-16 staging (m97).

#define BMg 128
#define BNg 128
#define BKg 32

typedef __attribute__((ext_vector_type(8))) short bf16x8;
typedef __attribute__((ext_vector_type(4))) float f32x4;

template <typename OutT, int RELU>
__global__ __launch_bounds__(256)
void gemm_mfma(const __hip_bfloat16* __restrict__ A,   // [Mpad, KDIM]
               const __hip_bfloat16* __restrict__ Bt,  // [256, KDIM]  (n-major)
               const float* __restrict__ bias,         // [256]
               OutT* __restrict__ C,                   // [N, 256]
               int Nrows) {
    __shared__ short As[BMg * BKg];
    __shared__ short Bs[BNg * BKg];
    int t = threadIdx.x;
    int lane = t & 63;
    int wave = t >> 6;
    int wm = wave & 1, wn = wave >> 1;
    size_t row0 = (size_t)blockIdx.x * BMg;
    size_t col0 = (size_t)blockIdx.y * BNg;

    const unsigned short* Ag = (const unsigned short*)A;
    const unsigned short* Bg = (const unsigned short*)Bt;

    float bb[4];
#pragma unroll
    for (int ni = 0; ni < 4; ni++) bb[ni] = bias[col0 + wn * 64 + ni * 16 + (lane & 15)];

    f32x4 acc[4][4] = {};

    for (int k0 = 0; k0 < KDIM; k0 += BKg) {
#pragma unroll
        for (int h = 0; h < 2; h++) {
            int c = t + h * 256;          // chunk id 0..511 (16B each)
            int r = c >> 2, p = c & 3;    // tile row, 16B part within 64B row
            const unsigned short* ga = Ag + (row0 + r) * KDIM + k0 + p * 8;
            __builtin_amdgcn_global_load_lds(
                (const __attribute__((address_space(1))) void*)ga,
                (__attribute__((address_space(3))) void*)((char*)As + c * 16),
                16, 0, 0);
            const unsigned short* gb = Bg + (col0 + r) * KDIM + k0 + p * 8;
            __builtin_amdgcn_global_load_lds(
                (const __attribute__((address_space(1))) void*)gb,
                (__attribute__((address_space(3))) void*)((char*)Bs + c * 16),
                16, 0, 0);
        }
        __syncthreads();

        bf16x8 af[4], bfr[4];
#pragma unroll
        for (int mi = 0; mi < 4; mi++)
            af[mi] = *(const bf16x8*)&As[(wm * 64 + mi * 16 + (lane & 15)) * BKg + (lane >> 4) * 8];
#pragma unroll
        for (int ni = 0; ni < 4; ni++)
            bfr[ni] = *(const bf16x8*)&Bs[(wn * 64 + ni * 16 + (lane & 15)) * BKg + (lane >> 4) * 8];
#pragma unroll
        for (int mi = 0; mi < 4; mi++)
#pragma unroll
            for (int ni = 0; ni < 4; ni++)
                acc[mi][ni] = __builtin_amdgcn_mfma_f32_16x16x32_bf16(af[mi], bfr[ni], acc[mi][ni], 0, 0, 0);
        __syncthreads();
    }

    // epilogue: C/D layout col=lane&15, row=(lane>>4)*4+j  [m89-verified]
#pragma unroll
    for (int mi = 0; mi < 4; mi++) {
#pragma unroll
        for (int j = 0; j < 4; j++) {
            size_t row = row0 + wm * 64 + mi * 16 + (lane >> 4) * 4 + j;
            if (row < (size_t)Nrows) {
#pragma unroll
                for (int ni = 0; ni < 4; ni++) {
                    size_t col = col0 + wn * 64 + ni * 16 + (lane & 15);
                    float v = acc[mi][ni][j] + bb[ni];
                    if (RELU) v = fmaxf(v, 0.f);
                    if constexpr (sizeof(OutT) == 2) {
                        ((unsigned short*)C)[row * DIM + col] = f2bf(v);
                    } else {
                        ((float*)C)[row * DIM + col] = v;
                    }
                }
            }
        }
    }
}

// ---------------- pooling + linear head ----------------

__global__ void colsum(const float* __restrict__ Hm, int N, float* __restrict__ g) {
    int t = threadIdx.x;       // one per column
    int r0 = blockIdx.x * 64;
    int rend = min(r0 + 64, N);
    float s = 0.f;
    for (int r = r0; r < rend; r++) s += Hm[(size_t)r * DIM + t];
    atomicAdd(&g[t], s);
}

__global__ void final_lin(const float* __restrict__ g, const float* __restrict__ lw,
                          const float* __restrict__ lb, float* __restrict__ out) {
    __shared__ float s0[256], s1[256];
    int t = threadIdx.x;
    float gv = g[t];
    s0[t] = gv * lw[t * 2 + 0];
    s1[t] = gv * lw[t * 2 + 1];
    __syncthreads();
    for (int off = 128; off > 0; off >>= 1) {
        if (t < off) { s0[t] += s0[t + off]; s1[t] += s1[t + off]; }
        __syncthreads();
    }
    if (t == 0) { out[0] = s0[0] + lb[0]; out[1] = s1[0] + lb[1]; }
}

// ---------------- launch ----------------

static inline char* align_up(char* p, size_t a) {
    return (char*)(((uintptr_t)p + (a - 1)) & ~(uintptr_t)(a - 1));
}

extern "C" void kernel_launch(void* const* d_in, const int* in_sizes, int n_in,
                              void* d_out, int out_size, void* d_ws, size_t ws_size,
                              hipStream_t stream) {
    const float* x     = (const float*)d_in[0];
    const int*   eidx  = (const int*)d_in[1];
    const int*   etype = (const int*)d_in[2];
    const float* W0    = (const float*)d_in[4];
    const float* root0 = (const float*)d_in[5];
    const float* b0    = (const float*)d_in[6];
    const float* W1    = (const float*)d_in[7];
    const float* root1 = (const float*)d_in[8];
    const float* b1    = (const float*)d_in[9];
    const float* lin_w = (const float*)d_in[10];
    const float* lin_b = (const float*)d_in[11];
    float* out = (float*)d_out;

    const int N = in_sizes[0] / DIM;
    const int E = in_sizes[2];
    const int RN = RREL * N;
    const int* src = eidx;
    const int* dst = eidx + E;

    const int gx = (N + BMg - 1) / BMg;
    const int Mpad = gx * BMg;

    char* w = (char*)d_ws;
    int* counts  = (int*)w; w += (size_t)RN * 4;
    int* cursors = (int*)w; w += (size_t)RN * 4;
    float* g     = (float*)w; w += 256 * 4;
    size_t zero_bytes = (size_t)RN * 8 + 1024;   // counts + cursors + g, contiguous
    int* offsets = (int*)w; w += (size_t)RN * 4;
    int nb = (RN + 255) / 256;
    int* bsums   = (int*)w; w += (size_t)nb * 4;
    int* elist   = (int*)w; w += (size_t)E * 4;
    w = align_up(w, 16);
    __hip_bfloat16* WT = (__hip_bfloat16*)w; w += (size_t)2 * DIM * KDIM * 2;
    w = align_up(w, 16);
    __hip_bfloat16* Y = (__hip_bfloat16*)w; w += (size_t)Mpad * KDIM * 2;
    w = align_up(w, 16);
    __hip_bfloat16* h1 = (__hip_bfloat16*)w; w += (size_t)N * DIM * 2;
    w = align_up(w, 16);
    float* h2 = (float*)w; w += (size_t)N * DIM * 4;

    hipMemsetAsync(counts, 0, zero_bytes, stream);

    int eb = (E + 255) / 256;
    count_edges<<<eb, 256, 0, stream>>>(etype, dst, counts, N, E);
    scan_part1<<<nb, 256, 0, stream>>>(counts, RN, bsums);
    scan_part2<<<1, 512, 0, stream>>>(bsums, nb);
    scan_part3<<<nb, 256, 0, stream>>>(counts, RN, bsums, offsets);
    scatter_edges<<<eb, 256, 0, stream>>>(etype, src, dst, offsets, cursors, elist, N, E);

    dim3 wtg(KDIM / 32, DIM / 32, 2);
    build_wt<<<wtg, 256, 0, stream>>>(W0, root0, W1, root1, WT);

    dim3 gg(gx, DIM / BNg);

    // layer 0
    aggregate<float><<<N, 320, 0, stream>>>(x, offsets, counts, elist, Y, N);
    gemm_mfma<__hip_bfloat16, 1><<<gg, 256, 0, stream>>>(Y, WT, b0, h1, N);
    // layer 1
    aggregate<__hip_bfloat16><<<N, 320, 0, stream>>>(h1, offsets, counts, elist, Y, N);
    gemm_mfma<float, 0><<<gg, 256, 0, stream>>>(Y, WT + (size_t)DIM * KDIM, b1, h2, N);

    // pool + head
    colsum<<<(N + 63) / 64, 256, 0, stream>>>(h2, N, g);
    final_lin<<<1, 256, 0, stream>>>(g, lin_w, lin_b, out);
}

// Round 3
// 368.608 us; speedup vs baseline: 2.2939x; 1.0107x over previous
//
#include <hip/hip_runtime.h>
#include <hip/hip_bf16.h>

#define RREL 4
#define DIM 256
#define KDIM 1280      // 4*DIM (means) + DIM (self)
#define KMEAN 1024     // means-only K extent of Y

__device__ __forceinline__ float bf2f(unsigned short u) {
    union { unsigned int i; float f; } z; z.i = ((unsigned int)u) << 16; return z.f;
}
__device__ __forceinline__ unsigned short f2bf(float f) {
    __hip_bfloat16 h = __float2bfloat16(f);
    return *(unsigned short*)&h;
}

// ---------------- CSR build ----------------

__global__ void count_edges(const int* __restrict__ etype, const int* __restrict__ dst,
                            int* __restrict__ counts, int N, int E) {
    int e = blockIdx.x * 256 + threadIdx.x;
    if (e < E) atomicAdd(&counts[etype[e] * N + dst[e]], 1);
}

__device__ __forceinline__ int wave_scan_incl(int v) {
    int lane = threadIdx.x & 63;
#pragma unroll
    for (int off = 1; off < 64; off <<= 1) {
        int n = __shfl_up(v, off, 64);
        if (lane >= off) v += n;
    }
    return v;
}

__device__ __forceinline__ int block_scan_256(int v) {
    __shared__ int wsm[8];
    int lane = threadIdx.x & 63;
    int wid = threadIdx.x >> 6;
    int incl = wave_scan_incl(v);
    if (lane == 63) wsm[wid] = incl;
    __syncthreads();
    if (threadIdx.x == 0) {
        int s = 0;
#pragma unroll
        for (int w = 0; w < 4; w++) { int t = wsm[w]; wsm[4 + w] = s; s += t; }
    }
    __syncthreads();
    return incl + wsm[4 + wid];
}

__global__ void scan_part1(const int* __restrict__ counts, int n, int* __restrict__ bsums) {
    int i = blockIdx.x * 256 + threadIdx.x;
    int v = (i < n) ? counts[i] : 0;
    int incl = block_scan_256(v);
    if (threadIdx.x == 255) bsums[blockIdx.x] = incl;
}

__global__ void scan_part2(int* __restrict__ bsums, int nb) {  // 1 block, 512 threads; nb <= 512
    __shared__ int wsm[16];
    int t = threadIdx.x;
    int v = (t < nb) ? bsums[t] : 0;
    int lane = t & 63, wid = t >> 6;
    int incl = wave_scan_incl(v);
    if (lane == 63) wsm[wid] = incl;
    __syncthreads();
    if (t == 0) {
        int s = 0;
#pragma unroll
        for (int w = 0; w < 8; w++) { int tv = wsm[w]; wsm[8 + w] = s; s += tv; }
    }
    __syncthreads();
    incl += wsm[8 + wid];
    if (t < nb) bsums[t] = incl - v;   // exclusive
}

__global__ void scan_part3(const int* __restrict__ counts, int n,
                           const int* __restrict__ bsums, int* __restrict__ offsets) {
    int i = blockIdx.x * 256 + threadIdx.x;
    int v = (i < n) ? counts[i] : 0;
    int incl = block_scan_256(v);
    if (i < n) offsets[i] = bsums[blockIdx.x] + incl - v;
}

__global__ void scatter_edges(const int* __restrict__ etype, const int* __restrict__ src,
                              const int* __restrict__ dst, const int* __restrict__ offsets,
                              int* __restrict__ cursors, int* __restrict__ elist, int N, int E) {
    int e = blockIdx.x * 256 + threadIdx.x;
    if (e < E) {
        int seg = etype[e] * N + dst[e];
        int p = atomicAdd(&cursors[seg], 1);
        elist[offsets[seg] + p] = src[e];
    }
}

// ---------------- x -> bf16 cast ----------------

__global__ void cast_bf16(const float* __restrict__ in, __hip_bfloat16* __restrict__ out, int n4) {
    int i = blockIdx.x * 256 + threadIdx.x;
    if (i < n4) {
        float4 v = ((const float4*)in)[i];
        ushort4 u = make_ushort4(f2bf(v.x), f2bf(v.y), f2bf(v.z), f2bf(v.w));
        ((ushort4*)out)[i] = u;
    }
}

// ---------------- weight transpose + bf16 cast: WT[layer][n][k], k in 0..1279 ----------------

__global__ __launch_bounds__(256)
void build_wt(const float* __restrict__ W0, const float* __restrict__ root0,
              const float* __restrict__ W1, const float* __restrict__ root1,
              __hip_bfloat16* __restrict__ WT) {
    __shared__ float tile[32][33];
    int layer = blockIdx.z;
    const float* Wm = layer ? W1 : W0;
    const float* Rm = layer ? root1 : root0;
    int k0 = blockIdx.x * 32, n0 = blockIdx.y * 32;
    int tx = threadIdx.x & 31, ty = threadIdx.x >> 5;   // 32x8
    const float* src;
    int kbase;
    if (k0 < RREL * DIM) { src = Wm; kbase = k0; } else { src = Rm; kbase = k0 - RREL * DIM; }
#pragma unroll
    for (int j = 0; j < 4; j++) {
        int k = kbase + ty + j * 8;
        tile[ty + j * 8][tx] = src[(size_t)k * DIM + n0 + tx];
    }
    __syncthreads();
#pragma unroll
    for (int j = 0; j < 4; j++) {
        int n = n0 + ty + j * 8;
        WT[((size_t)layer * DIM + n) * KDIM + k0 + tx] = __float2bfloat16(tile[tx][ty + j * 8]);
    }
}

// ---------------- aggregation: Y[i] = [mean_r(feat) x4]  (bf16, means only) ----------------
// 256 threads = 4 waves, one per relation. Lane owns 4 dims (8B vec loads);
// 4-deep unroll keeps 4 row-loads in flight.

__global__ __launch_bounds__(256)
void aggregate(const __hip_bfloat16* __restrict__ feat, const int* __restrict__ offsets,
               const int* __restrict__ counts, const int* __restrict__ elist,
               __hip_bfloat16* __restrict__ Y, int N) {
    int i = blockIdx.x;
    int wave = threadIdx.x >> 6, lane = threadIdx.x & 63;
    const unsigned short* fu = (const unsigned short*)feat;
    unsigned short* Yu = (unsigned short*)Y;
    int seg = wave * N + i;
    int beg = offsets[seg];
    int cnt = counts[seg];
    float ax = 0.f, ay = 0.f, az = 0.f, aw = 0.f;
    int k = 0;
    for (; k + 4 <= cnt; k += 4) {
        int i0 = elist[beg + k + 0];
        int i1 = elist[beg + k + 1];
        int i2 = elist[beg + k + 2];
        int i3 = elist[beg + k + 3];
        ushort4 r0 = *(const ushort4*)(fu + (size_t)i0 * DIM + lane * 4);
        ushort4 r1 = *(const ushort4*)(fu + (size_t)i1 * DIM + lane * 4);
        ushort4 r2 = *(const ushort4*)(fu + (size_t)i2 * DIM + lane * 4);
        ushort4 r3 = *(const ushort4*)(fu + (size_t)i3 * DIM + lane * 4);
        ax += bf2f(r0.x) + bf2f(r1.x) + bf2f(r2.x) + bf2f(r3.x);
        ay += bf2f(r0.y) + bf2f(r1.y) + bf2f(r2.y) + bf2f(r3.y);
        az += bf2f(r0.z) + bf2f(r1.z) + bf2f(r2.z) + bf2f(r3.z);
        aw += bf2f(r0.w) + bf2f(r1.w) + bf2f(r2.w) + bf2f(r3.w);
    }
    for (; k < cnt; k++) {
        int idx = elist[beg + k];
        ushort4 r = *(const ushort4*)(fu + (size_t)idx * DIM + lane * 4);
        ax += bf2f(r.x); ay += bf2f(r.y); az += bf2f(r.z); aw += bf2f(r.w);
    }
    float inv = (cnt > 0) ? 1.f / (float)cnt : 0.f;
    ushort4 u = make_ushort4(f2bf(ax * inv), f2bf(ay * inv), f2bf(az * inv), f2bf(aw * inv));
    *(ushort4*)(Yu + (size_t)i * KMEAN + wave * DIM + lane * 4) = u;
}

// ---------------- MFMA GEMM, double-buffered ----------------
// C[N,256] = [Y | self] @ WT^T + bias.  A-tile k<1024 from Y [Mpad,1024];
// k>=1024 from Aself [*,256] (the feature table itself — self slice never
// materialized).  Tile 128x64, BK=64, 256 threads = 4 waves (2 row-halves x
// 2 col-halves), wave = 4x2 fragments of mfma_f32_16x16x32_bf16.
// Prefetch issued AFTER __syncthreads so the barrier never drains it.

#define BMg 128
#define BNg 64
#define BKg 64

typedef __attribute__((ext_vector_type(8))) short bf16x8;
typedef __attribute__((ext_vector_type(4))) float f32x4;

template <typename OutT, int RELU>
__global__ __launch_bounds__(256)
void gemm_mfma(const __hip_bfloat16* __restrict__ A,     // [Mpad, 1024] means
               const __hip_bfloat16* __restrict__ Aself, // [>=N, 256] feature table
               const __hip_bfloat16* __restrict__ Bt,    // [256, 1280] n-major
               const float* __restrict__ bias,           // [256]
               OutT* __restrict__ C,                     // [N, 256]
               int Nrows) {
    __shared__ short As[2][BMg * BKg];
    __shared__ short Bs[2][BNg * BKg];
    int t = threadIdx.x;
    int lane = t & 63;
    int wave = t >> 6;
    int wm = wave & 1, wn = wave >> 1;
    size_t row0 = (size_t)blockIdx.x * BMg;
    size_t col0 = (size_t)blockIdx.y * BNg;

    const unsigned short* Ag = (const unsigned short*)A;
    const unsigned short* Sg = (const unsigned short*)Aself;
    const unsigned short* Bg = (const unsigned short*)Bt;

    float bb[2];
#pragma unroll
    for (int ni = 0; ni < 2; ni++) bb[ni] = bias[col0 + wn * 32 + ni * 16 + (lane & 15)];

    f32x4 acc[4][2] = {};

    auto issue_tile = [&](int k0, short* as, short* bs) {
        const unsigned short* Abase;
        int kk, stride;
        if (k0 < KMEAN) { Abase = Ag; kk = k0; stride = KMEAN; }
        else            { Abase = Sg; kk = k0 - KMEAN; stride = DIM; }
#pragma unroll
        for (int h = 0; h < 4; h++) {              // A: 1024 chunks of 16B
            int c = t + h * 256;
            int r = c >> 3, p = c & 7;
            const unsigned short* ga = Abase + (row0 + r) * stride + kk + p * 8;
            __builtin_amdgcn_global_load_lds(
                (const __attribute__((address_space(1))) void*)ga,
                (__attribute__((address_space(3))) void*)((char*)as + c * 16),
                16, 0, 0);
        }
#pragma unroll
        for (int h = 0; h < 2; h++) {              // B: 512 chunks of 16B
            int c = t + h * 256;
            int r = c >> 3, p = c & 7;
            const unsigned short* gb = Bg + (col0 + r) * KDIM + k0 + p * 8;
            __builtin_amdgcn_global_load_lds(
                (const __attribute__((address_space(1))) void*)gb,
                (__attribute__((address_space(3))) void*)((char*)bs + c * 16),
                16, 0, 0);
        }
    };

    issue_tile(0, As[0], Bs[0]);
    int cur = 0;
    for (int k0 = 0; k0 < KDIM; k0 += BKg) {
        __syncthreads();                               // drains tile-k loads
        if (k0 + BKg < KDIM) issue_tile(k0 + BKg, As[cur ^ 1], Bs[cur ^ 1]);
        const short* as = As[cur];
        const short* bs = Bs[cur];
#pragma unroll
        for (int ks = 0; ks < 2; ks++) {
            bf16x8 af[4], bfr[2];
#pragma unroll
            for (int mi = 0; mi < 4; mi++)
                af[mi] = *(const bf16x8*)&as[(wm * 64 + mi * 16 + (lane & 15)) * BKg + ks * 32 + (lane >> 4) * 8];
#pragma unroll
            for (int ni = 0; ni < 2; ni++)
                bfr[ni] = *(const bf16x8*)&bs[(wn * 32 + ni * 16 + (lane & 15)) * BKg + ks * 32 + (lane >> 4) * 8];
#pragma unroll
            for (int mi = 0; mi < 4; mi++)
#pragma unroll
                for (int ni = 0; ni < 2; ni++)
                    acc[mi][ni] = __builtin_amdgcn_mfma_f32_16x16x32_bf16(af[mi], bfr[ni], acc[mi][ni], 0, 0, 0);
        }
        cur ^= 1;
    }

    // epilogue: C/D layout col=lane&15, row=(lane>>4)*4+j  [m89-verified]
#pragma unroll
    for (int mi = 0; mi < 4; mi++) {
#pragma unroll
        for (int j = 0; j < 4; j++) {
            size_t row = row0 + wm * 64 + mi * 16 + (lane >> 4) * 4 + j;
            if (row < (size_t)Nrows) {
#pragma unroll
                for (int ni = 0; ni < 2; ni++) {
                    size_t col = col0 + wn * 32 + ni * 16 + (lane & 15);
                    float v = acc[mi][ni][j] + bb[ni];
                    if (RELU) v = fmaxf(v, 0.f);
                    if constexpr (sizeof(OutT) == 2) {
                        ((unsigned short*)C)[row * DIM + col] = f2bf(v);
                    } else {
                        ((float*)C)[row * DIM + col] = v;
                    }
                }
            }
        }
    }
}

// ---------------- pooling + linear head ----------------

__global__ void colsum(const float* __restrict__ Hm, int N, float* __restrict__ g) {
    int t = threadIdx.x;       // one per column
    int r0 = blockIdx.x * 64;
    int rend = min(r0 + 64, N);
    float s = 0.f;
    for (int r = r0; r < rend; r++) s += Hm[(size_t)r * DIM + t];
    atomicAdd(&g[t], s);
}

__global__ void final_lin(const float* __restrict__ g, const float* __restrict__ lw,
                          const float* __restrict__ lb, float* __restrict__ out) {
    __shared__ float s0[256], s1[256];
    int t = threadIdx.x;
    float gv = g[t];
    s0[t] = gv * lw[t * 2 + 0];
    s1[t] = gv * lw[t * 2 + 1];
    __syncthreads();
    for (int off = 128; off > 0; off >>= 1) {
        if (t < off) { s0[t] += s0[t + off]; s1[t] += s1[t + off]; }
        __syncthreads();
    }
    if (t == 0) { out[0] = s0[0] + lb[0]; out[1] = s1[0] + lb[1]; }
}

// ---------------- launch ----------------

static inline char* align_up(char* p, size_t a) {
    return (char*)(((uintptr_t)p + (a - 1)) & ~(uintptr_t)(a - 1));
}

extern "C" void kernel_launch(void* const* d_in, const int* in_sizes, int n_in,
                              void* d_out, int out_size, void* d_ws, size_t ws_size,
                              hipStream_t stream) {
    const float* x     = (const float*)d_in[0];
    const int*   eidx  = (const int*)d_in[1];
    const int*   etype = (const int*)d_in[2];
    const float* W0    = (const float*)d_in[4];
    const float* root0 = (const float*)d_in[5];
    const float* b0    = (const float*)d_in[6];
    const float* W1    = (const float*)d_in[7];
    const float* root1 = (const float*)d_in[8];
    const float* b1    = (const float*)d_in[9];
    const float* lin_w = (const float*)d_in[10];
    const float* lin_b = (const float*)d_in[11];
    float* out = (float*)d_out;

    const int N = in_sizes[0] / DIM;
    const int E = in_sizes[2];
    const int RN = RREL * N;
    const int* src = eidx;
    const int* dst = eidx + E;

    const int gx = (N + BMg - 1) / BMg;
    const int Mpad = gx * BMg;

    char* w = (char*)d_ws;
    int* counts  = (int*)w; w += (size_t)RN * 4;
    int* cursors = (int*)w; w += (size_t)RN * 4;
    float* g     = (float*)w; w += 256 * 4;
    size_t zero_bytes = (size_t)RN * 8 + 1024;   // counts + cursors + g, contiguous
    int* offsets = (int*)w; w += (size_t)RN * 4;
    int nb = (RN + 255) / 256;
    int* bsums   = (int*)w; w += (size_t)nb * 4;
    int* elist   = (int*)w; w += (size_t)E * 4;
    w = align_up(w, 16);
    __hip_bfloat16* WT = (__hip_bfloat16*)w; w += (size_t)2 * DIM * KDIM * 2;
    w = align_up(w, 16);
    __hip_bfloat16* Y  = (__hip_bfloat16*)w; w += (size_t)Mpad * KMEAN * 2;
    // keep xb, h1, h2 adjacent: padded-row overreads (rows N..Mpad-1) from
    // xb/h1 land in the next buffer — in-bounds of ws, values unused.
    __hip_bfloat16* xb = (__hip_bfloat16*)w; w += (size_t)N * DIM * 2;
    __hip_bfloat16* h1 = (__hip_bfloat16*)w; w += (size_t)N * DIM * 2;
    float* h2 = (float*)w; w += (size_t)Mpad * DIM * 4;

    hipMemsetAsync(counts, 0, zero_bytes, stream);

    int eb = (E + 255) / 256;
    count_edges<<<eb, 256, 0, stream>>>(etype, dst, counts, N, E);
    scan_part1<<<nb, 256, 0, stream>>>(counts, RN, bsums);
    scan_part2<<<1, 512, 0, stream>>>(bsums, nb);
    scan_part3<<<nb, 256, 0, stream>>>(counts, RN, bsums, offsets);
    scatter_edges<<<eb, 256, 0, stream>>>(etype, src, dst, offsets, cursors, elist, N, E);

    dim3 wtg(KDIM / 32, DIM / 32, 2);
    build_wt<<<wtg, 256, 0, stream>>>(W0, root0, W1, root1, WT);
    cast_bf16<<<(N * DIM / 4 + 255) / 256, 256, 0, stream>>>(x, xb, N * DIM / 4);

    dim3 gg(gx, DIM / BNg);

    // layer 0
    aggregate<<<N, 256, 0, stream>>>(xb, offsets, counts, elist, Y, N);
    gemm_mfma<__hip_bfloat16, 1><<<gg, 256, 0, stream>>>(Y, xb, WT, b0, h1, N);
    // layer 1
    aggregate<<<N, 256, 0, stream>>>(h1, offsets, counts, elist, Y, N);
    gemm_mfma<float, 0><<<gg, 256, 0, stream>>>(Y, h1, WT + (size_t)DIM * KDIM, b1, h2, N);

    // pool + head
    colsum<<<(N + 63) / 64, 256, 0, stream>>>(h2, N, g);
    final_lin<<<1, 256, 0, stream>>>(g, lin_w, lin_b, out);
}

// Round 4
// 325.457 us; speedup vs baseline: 2.5980x; 1.1326x over previous
//
#include <hip/hip_runtime.h>
#include <hip/hip_bf16.h>

#define RREL 4
#define DIM 256
#define KDIM 1280      // 4*DIM (means) + DIM (self)
#define KMEAN 1024     // means-only K extent of Y

__device__ __forceinline__ float bf2f(unsigned short u) {
    union { unsigned int i; float f; } z; z.i = ((unsigned int)u) << 16; return z.f;
}
__device__ __forceinline__ unsigned short f2bf(float f) {
    __hip_bfloat16 h = __float2bfloat16(f);
    return *(unsigned short*)&h;
}

typedef __attribute__((ext_vector_type(8))) short bf16x8;
typedef __attribute__((ext_vector_type(8))) unsigned short u16x8;
typedef __attribute__((ext_vector_type(4))) float f32x4;

// ---------------- CSR build ----------------

__global__ void count_edges(const int* __restrict__ etype, const int* __restrict__ dst,
                            int* __restrict__ counts, int N, int E) {
    int e = blockIdx.x * 256 + threadIdx.x;
    if (e < E) atomicAdd(&counts[etype[e] * N + dst[e]], 1);
}

__device__ __forceinline__ int wave_scan_incl(int v) {
    int lane = threadIdx.x & 63;
#pragma unroll
    for (int off = 1; off < 64; off <<= 1) {
        int n = __shfl_up(v, off, 64);
        if (lane >= off) v += n;
    }
    return v;
}

__device__ __forceinline__ int block_scan_256(int v) {
    __shared__ int wsm[8];
    int lane = threadIdx.x & 63;
    int wid = threadIdx.x >> 6;
    int incl = wave_scan_incl(v);
    if (lane == 63) wsm[wid] = incl;
    __syncthreads();
    if (threadIdx.x == 0) {
        int s = 0;
#pragma unroll
        for (int w = 0; w < 4; w++) { int t = wsm[w]; wsm[4 + w] = s; s += t; }
    }
    __syncthreads();
    return incl + wsm[4 + wid];
}

__global__ void scan_part1(const int* __restrict__ counts, int n, int* __restrict__ bsums) {
    int i = blockIdx.x * 256 + threadIdx.x;
    int v = (i < n) ? counts[i] : 0;
    int incl = block_scan_256(v);
    if (threadIdx.x == 255) bsums[blockIdx.x] = incl;
}

__global__ void scan_part2(int* __restrict__ bsums, int nb) {  // 1 block, 512 threads; nb <= 512
    __shared__ int wsm[16];
    int t = threadIdx.x;
    int v = (t < nb) ? bsums[t] : 0;
    int lane = t & 63, wid = t >> 6;
    int incl = wave_scan_incl(v);
    if (lane == 63) wsm[wid] = incl;
    __syncthreads();
    if (t == 0) {
        int s = 0;
#pragma unroll
        for (int w = 0; w < 8; w++) { int tv = wsm[w]; wsm[8 + w] = s; s += tv; }
    }
    __syncthreads();
    incl += wsm[8 + wid];
    if (t < nb) bsums[t] = incl - v;   // exclusive
}

__global__ void scan_part3(const int* __restrict__ counts, int n,
                           const int* __restrict__ bsums, int* __restrict__ offsets) {
    int i = blockIdx.x * 256 + threadIdx.x;
    int v = (i < n) ? counts[i] : 0;
    int incl = block_scan_256(v);
    if (i < n) offsets[i] = bsums[blockIdx.x] + incl - v;
}

__global__ void scatter_edges(const int* __restrict__ etype, const int* __restrict__ src,
                              const int* __restrict__ dst, const int* __restrict__ offsets,
                              int* __restrict__ cursors, int* __restrict__ elist, int N, int E) {
    int e = blockIdx.x * 256 + threadIdx.x;
    if (e < E) {
        int seg = etype[e] * N + dst[e];
        int p = atomicAdd(&cursors[seg], 1);
        elist[offsets[seg] + p] = src[e];
    }
}

// ---------------- x -> bf16 cast ----------------

__global__ void cast_bf16(const float* __restrict__ in, __hip_bfloat16* __restrict__ out, int n4) {
    int i = blockIdx.x * 256 + threadIdx.x;
    if (i < n4) {
        float4 v = ((const float4*)in)[i];
        ushort4 u = make_ushort4(f2bf(v.x), f2bf(v.y), f2bf(v.z), f2bf(v.w));
        ((ushort4*)out)[i] = u;
    }
}

// ---------------- weight transpose + bf16 cast: WT[layer][n][k], k in 0..1279 ----------------

__global__ __launch_bounds__(256)
void build_wt(const float* __restrict__ W0, const float* __restrict__ root0,
              const float* __restrict__ W1, const float* __restrict__ root1,
              __hip_bfloat16* __restrict__ WT) {
    __shared__ float tile[32][33];
    int layer = blockIdx.z;
    const float* Wm = layer ? W1 : W0;
    const float* Rm = layer ? root1 : root0;
    int k0 = blockIdx.x * 32, n0 = blockIdx.y * 32;
    int tx = threadIdx.x & 31, ty = threadIdx.x >> 5;   // 32x8
    const float* src;
    int kbase;
    if (k0 < RREL * DIM) { src = Wm; kbase = k0; } else { src = Rm; kbase = k0 - RREL * DIM; }
#pragma unroll
    for (int j = 0; j < 4; j++) {
        int k = kbase + ty + j * 8;
        tile[ty + j * 8][tx] = src[(size_t)k * DIM + n0 + tx];
    }
    __syncthreads();
#pragma unroll
    for (int j = 0; j < 4; j++) {
        int n = n0 + ty + j * 8;
        WT[((size_t)layer * DIM + n) * KDIM + k0 + tx] = __float2bfloat16(tile[tx][ty + j * 8]);
    }
}

// ---------------- aggregation: Y[i] = [mean_r(feat) x4]  (bf16, means only) ----------------
// 256 threads = 4 waves, one per relation (avg segment size E/(R*N) = 4).
// Wave processes 2 edges per 16B/lane load: lanes 0-31 cover edge e0's 256
// dims, lanes 32-63 edge e1's. Halves combined via shfl_xor(32) at the end.

__global__ __launch_bounds__(256)
void aggregate(const __hip_bfloat16* __restrict__ feat, const int* __restrict__ offsets,
               const int* __restrict__ counts, const int* __restrict__ elist,
               __hip_bfloat16* __restrict__ Y, int N) {
    int i = blockIdx.x;
    int wave = threadIdx.x >> 6, lane = threadIdx.x & 63;
    int half = lane >> 5, li = lane & 31;
    const unsigned short* fu = (const unsigned short*)feat;
    unsigned short* Yu = (unsigned short*)Y;
    int seg = wave * N + i;
    int beg = offsets[seg];
    int cnt = counts[seg];
    float a[8] = {};
    int k = 0;
    for (; k + 4 <= cnt; k += 4) {
        int e0 = elist[beg + k + half];
        int e1 = elist[beg + k + 2 + half];
        u16x8 r0 = *(const u16x8*)(fu + (size_t)e0 * DIM + li * 8);
        u16x8 r1 = *(const u16x8*)(fu + (size_t)e1 * DIM + li * 8);
#pragma unroll
        for (int j = 0; j < 8; j++) a[j] += bf2f(r0[j]) + bf2f(r1[j]);
    }
    for (; k < cnt; k += 2) {
        bool valid = (k + half) < cnt;
        int e = elist[beg + (valid ? k + half : k)];
        u16x8 r = *(const u16x8*)(fu + (size_t)e * DIM + li * 8);
        if (valid) {
#pragma unroll
            for (int j = 0; j < 8; j++) a[j] += bf2f(r[j]);
        }
    }
#pragma unroll
    for (int j = 0; j < 8; j++) a[j] += __shfl_xor(a[j], 32, 64);
    if (half == 0) {
        float inv = (cnt > 0) ? 1.f / (float)cnt : 0.f;
        u16x8 u;
#pragma unroll
        for (int j = 0; j < 8; j++) u[j] = f2bf(a[j] * inv);
        *(u16x8*)(Yu + (size_t)i * KMEAN + wave * DIM + li * 8) = u;
    }
}

// ---------------- MFMA GEMM, double-buffered, full-width N ----------------
// C[N,256] = [Y | self] @ WT^T + bias.  BM=64, BN=256 (gy=1: Y fetched ONCE),
// BK=64. 256 threads = 4 waves, wave w owns cols w*64..w*64+63 (4x4 frags of
// 16x16x32). LDS XOR-swizzled via the global side of global_load_lds (per-lane
// global scatter is legal; LDS side stays lane-linear).
// MODE 0: write bf16 + ReLU.  MODE 1: no C write; fused column-sum atomicAdd.

#define BMg 64
#define BKg 64

template <int MODE>
__global__ __launch_bounds__(256)
void gemm_mfma(const __hip_bfloat16* __restrict__ A,     // [Mpad, 1024] means
               const __hip_bfloat16* __restrict__ Aself, // [Mpad, 256] feature table
               const __hip_bfloat16* __restrict__ Bt,    // [256, 1280] n-major
               const float* __restrict__ bias,           // [256]
               unsigned short* __restrict__ Cbf,         // [N, 256] (MODE 0)
               float* __restrict__ gsum,                 // [256]    (MODE 1)
               int Nrows) {
    __shared__ short As[2][BMg * BKg];       // 2 x 8 KB
    __shared__ short Bs[2][DIM * BKg];       // 2 x 32 KB
    int t = threadIdx.x;
    int lane = t & 63;
    int w = t >> 6;
    size_t row0 = (size_t)blockIdx.x * BMg;

    const unsigned short* Ag = (const unsigned short*)A;
    const unsigned short* Sg = (const unsigned short*)Aself;
    const unsigned short* Bg = (const unsigned short*)Bt;

    float bb[4];
#pragma unroll
    for (int ni = 0; ni < 4; ni++) bb[ni] = bias[w * 64 + ni * 16 + (lane & 15)];

    f32x4 acc[4][4] = {};

    auto issue_tile = [&](int k0, short* as, short* bs) {
        const unsigned short* Abase;
        int kk, stride;
        if (k0 < KMEAN) { Abase = Ag; kk = k0; stride = KMEAN; }
        else            { Abase = Sg; kk = k0 - KMEAN; stride = DIM; }
#pragma unroll
        for (int h = 0; h < 2; h++) {              // A: 512 chunks of 16B
            int c = t + h * 256;
            int r = c >> 3, pl = c & 7, pg = pl ^ (r & 7);
            const unsigned short* ga = Abase + (row0 + r) * stride + kk + pg * 8;
            __builtin_amdgcn_global_load_lds(
                (const __attribute__((address_space(1))) void*)ga,
                (__attribute__((address_space(3))) void*)((char*)as + c * 16),
                16, 0, 0);
        }
#pragma unroll
        for (int h = 0; h < 8; h++) {              // B: 2048 chunks of 16B
            int c = t + h * 256;
            int r = c >> 3, pl = c & 7, pg = pl ^ (r & 7);
            const unsigned short* gb = Bg + (size_t)r * KDIM + k0 + pg * 8;
            __builtin_amdgcn_global_load_lds(
                (const __attribute__((address_space(1))) void*)gb,
                (__attribute__((address_space(3))) void*)((char*)bs + c * 16),
                16, 0, 0);
        }
    };

    issue_tile(0, As[0], Bs[0]);
    int cur = 0;
    for (int k0 = 0; k0 < KDIM; k0 += BKg) {
        __syncthreads();                           // drains this tile's loads
        if (k0 + BKg < KDIM) issue_tile(k0 + BKg, As[cur ^ 1], Bs[cur ^ 1]);
        const short* as = As[cur];
        const short* bs = Bs[cur];
#pragma unroll
        for (int ks = 0; ks < 2; ks++) {
            int p = ks * 4 + (lane >> 4);          // 16B part index 0..7
            bf16x8 af[4], bfr[4];
#pragma unroll
            for (int mi = 0; mi < 4; mi++) {
                int m = mi * 16 + (lane & 15);
                af[mi] = *(const bf16x8*)&as[m * 64 + (p ^ (m & 7)) * 8];
            }
#pragma unroll
            for (int ni = 0; ni < 4; ni++) {
                int n = w * 64 + ni * 16 + (lane & 15);
                bfr[ni] = *(const bf16x8*)&bs[n * 64 + (p ^ (n & 7)) * 8];
            }
#pragma unroll
            for (int mi = 0; mi < 4; mi++)
#pragma unroll
                for (int ni = 0; ni < 4; ni++)
                    acc[mi][ni] = __builtin_amdgcn_mfma_f32_16x16x32_bf16(af[mi], bfr[ni], acc[mi][ni], 0, 0, 0);
        }
        cur ^= 1;
    }

    // C/D layout: col=lane&15, row=(lane>>4)*4+j  [m89-verified]
    if (MODE == 0) {
#pragma unroll
        for (int mi = 0; mi < 4; mi++) {
#pragma unroll
            for (int j = 0; j < 4; j++) {
                size_t row = row0 + mi * 16 + (lane >> 4) * 4 + j;
                if (row < (size_t)Nrows) {
#pragma unroll
                    for (int ni = 0; ni < 4; ni++) {
                        size_t col = w * 64 + ni * 16 + (lane & 15);
                        float v = fmaxf(acc[mi][ni][j] + bb[ni], 0.f);
                        Cbf[row * DIM + col] = f2bf(v);
                    }
                }
            }
        }
    } else {
        float cs[4] = {};
#pragma unroll
        for (int ni = 0; ni < 4; ni++) {
#pragma unroll
            for (int mi = 0; mi < 4; mi++)
#pragma unroll
                for (int j = 0; j < 4; j++) {
                    size_t row = row0 + mi * 16 + (lane >> 4) * 4 + j;
                    if (row < (size_t)Nrows) cs[ni] += acc[mi][ni][j] + bb[ni];
                }
            cs[ni] += __shfl_xor(cs[ni], 16, 64);
            cs[ni] += __shfl_xor(cs[ni], 32, 64);
        }
        if (lane < 16) {
#pragma unroll
            for (int ni = 0; ni < 4; ni++)
                atomicAdd(&gsum[w * 64 + ni * 16 + lane], cs[ni]);
        }
    }
}

// ---------------- linear head ----------------

__global__ void final_lin(const float* __restrict__ g, const float* __restrict__ lw,
                          const float* __restrict__ lb, float* __restrict__ out) {
    __shared__ float s0[256], s1[256];
    int t = threadIdx.x;
    float gv = g[t];
    s0[t] = gv * lw[t * 2 + 0];
    s1[t] = gv * lw[t * 2 + 1];
    __syncthreads();
    for (int off = 128; off > 0; off >>= 1) {
        if (t < off) { s0[t] += s0[t + off]; s1[t] += s1[t + off]; }
        __syncthreads();
    }
    if (t == 0) { out[0] = s0[0] + lb[0]; out[1] = s1[0] + lb[1]; }
}

// ---------------- launch ----------------

static inline char* align_up(char* p, size_t a) {
    return (char*)(((uintptr_t)p + (a - 1)) & ~(uintptr_t)(a - 1));
}

extern "C" void kernel_launch(void* const* d_in, const int* in_sizes, int n_in,
                              void* d_out, int out_size, void* d_ws, size_t ws_size,
                              hipStream_t stream) {
    const float* x     = (const float*)d_in[0];
    const int*   eidx  = (const int*)d_in[1];
    const int*   etype = (const int*)d_in[2];
    const float* W0    = (const float*)d_in[4];
    const float* root0 = (const float*)d_in[5];
    const float* b0    = (const float*)d_in[6];
    const float* W1    = (const float*)d_in[7];
    const float* root1 = (const float*)d_in[8];
    const float* b1    = (const float*)d_in[9];
    const float* lin_w = (const float*)d_in[10];
    const float* lin_b = (const float*)d_in[11];
    float* out = (float*)d_out;

    const int N = in_sizes[0] / DIM;
    const int E = in_sizes[2];
    const int RN = RREL * N;
    const int* src = eidx;
    const int* dst = eidx + E;

    const int gx = (N + BMg - 1) / BMg;
    const int Mpad = gx * BMg;

    char* w = (char*)d_ws;
    int* counts  = (int*)w; w += (size_t)RN * 4;
    int* cursors = (int*)w; w += (size_t)RN * 4;
    float* g     = (float*)w; w += 256 * 4;
    size_t zero_bytes = (size_t)RN * 8 + 1024;   // counts + cursors + g, contiguous
    int* offsets = (int*)w; w += (size_t)RN * 4;
    int nb = (RN + 255) / 256;
    int* bsums   = (int*)w; w += (size_t)nb * 4;
    int* elist   = (int*)w; w += (size_t)E * 4;
    w = align_up(w, 16);
    __hip_bfloat16* WT = (__hip_bfloat16*)w; w += (size_t)2 * DIM * KDIM * 2;
    w = align_up(w, 16);
    __hip_bfloat16* Y  = (__hip_bfloat16*)w; w += (size_t)Mpad * KMEAN * 2;
    __hip_bfloat16* xb = (__hip_bfloat16*)w; w += (size_t)Mpad * DIM * 2;   // Mpad rows: pad-row reads stay in-bounds
    __hip_bfloat16* h1 = (__hip_bfloat16*)w; w += (size_t)Mpad * DIM * 2;

    hipMemsetAsync(counts, 0, zero_bytes, stream);

    int eb = (E + 255) / 256;
    count_edges<<<eb, 256, 0, stream>>>(etype, dst, counts, N, E);
    scan_part1<<<nb, 256, 0, stream>>>(counts, RN, bsums);
    scan_part2<<<1, 512, 0, stream>>>(bsums, nb);
    scan_part3<<<nb, 256, 0, stream>>>(counts, RN, bsums, offsets);
    scatter_edges<<<eb, 256, 0, stream>>>(etype, src, dst, offsets, cursors, elist, N, E);

    dim3 wtg(KDIM / 32, DIM / 32, 2);
    build_wt<<<wtg, 256, 0, stream>>>(W0, root0, W1, root1, WT);
    cast_bf16<<<(N * DIM / 4 + 255) / 256, 256, 0, stream>>>(x, xb, N * DIM / 4);

    // layer 0: h1 = relu([Y|x] @ Wcat0 + b0), bf16
    aggregate<<<N, 256, 0, stream>>>(xb, offsets, counts, elist, Y, N);
    gemm_mfma<0><<<gx, 256, 0, stream>>>(Y, xb, WT, b0, (unsigned short*)h1, nullptr, N);
    // layer 1: g += colsum([Y|h1] @ Wcat1 + b1)  (h2 never materialized)
    aggregate<<<N, 256, 0, stream>>>(h1, offsets, counts, elist, Y, N);
    gemm_mfma<1><<<gx, 256, 0, stream>>>(Y, h1, WT + (size_t)DIM * KDIM, b1, nullptr, g, N);

    final_lin<<<1, 256, 0, stream>>>(g, lin_w, lin_b, out);
}